// Round 14
// baseline (529.656 us; speedup 1.0000x reference)
//
#include <hip/hip_runtime.h>

#define DM    1024
#define DFF   4096
#define SEQ   2048
#define BATCH 4
#define NROWS (BATCH * SEQ)   // 8192
#define HEADS 16
#define DKH   64
#define KSTR  (2 * DM)        // fused QK row stride

typedef __attribute__((ext_vector_type(4))) float          f32x4;
typedef __attribute__((ext_vector_type(8))) __bf16         bf16x8;
typedef __attribute__((ext_vector_type(8))) unsigned short u16x8;
typedef __attribute__((ext_vector_type(4))) unsigned short u16x4;

static __device__ __forceinline__ unsigned short f2bf(float f) {
  unsigned u = __builtin_bit_cast(unsigned, f);
  u += 0x7fffu + ((u >> 16) & 1u);   // round-to-nearest-even
  return (unsigned short)(u >> 16);
}

// ---------------- fp32 -> bf16 weight conversion ----------------
__global__ void k_f2bf(const float* __restrict__ in, unsigned short* __restrict__ out, int n4) {
  int i = blockIdx.x * blockDim.x + threadIdx.x;
  if (i >= n4) return;
  float4 v = reinterpret_cast<const float4*>(in)[i];
  ushort4 o;
  o.x = f2bf(v.x); o.y = f2bf(v.y); o.z = f2bf(v.z); o.w = f2bf(v.w);
  reinterpret_cast<ushort4*>(out)[i] = o;
}

// ---------------- RMSNorm: fp32 in -> bf16 out ----------------
__global__ __launch_bounds__(256) void k_rmsnorm(const float* __restrict__ x,
                                                 const float* __restrict__ w,
                                                 unsigned short* __restrict__ out) {
  const int row = blockIdx.x;
  const float4 v = reinterpret_cast<const float4*>(x + (size_t)row * DM)[threadIdx.x];
  float ss = v.x * v.x + v.y * v.y + v.z * v.z + v.w * v.w;
#pragma unroll
  for (int off = 32; off > 0; off >>= 1) ss += __shfl_down(ss, off);
  __shared__ float red[4];
  if ((threadIdx.x & 63) == 0) red[threadIdx.x >> 6] = ss;
  __syncthreads();
  const float tot  = red[0] + red[1] + red[2] + red[3];
  const float rden = rsqrtf(tot * (1.0f / DM) + 1e-5f);
  const float4 wv = reinterpret_cast<const float4*>(w)[threadIdx.x];
  ushort4 o;
  o.x = f2bf(v.x * wv.x * rden);
  o.y = f2bf(v.y * wv.y * rden);
  o.z = f2bf(v.z * wv.z * rden);
  o.w = f2bf(v.w * wv.w * rden);
  reinterpret_cast<ushort4*>(out + (size_t)row * DM)[threadIdx.x] = o;
}

// ---------------- NT GEMM: C(MxN) = A(MxK,bf16) * B(NxK,bf16)^T ----------------
// Round-9-proven structure, templated on tile width TN (128 or 256).
// 128xTN tile, 4 waves (2x2), wave tile 64 x TN/2; double-buffered 2-phase
// K-loop; row-major [rows][32] LDS with COALESCED staging (4 lanes per 64B
// row) + granule XOR. Round-10 lesson: do NOT trade staging coalescing for
// LDS-conflict-freedom (lost 40%). TN=256 cuts LDS bytes/FLOP by 1.33x;
// use only when grid >= 2 blocks/CU. EPI: 0 bf16, 1 fp32+res, 2 gelu,
// 3 bf16 with Q-half pre-scaled by 0.125*log2e.
template <int EPI, int TN>
__global__ __launch_bounds__(256, 2) void k_gemm_nt(const unsigned short* __restrict__ A,
                                                    const unsigned short* __restrict__ B,
                                                    void* __restrict__ Cv,
                                                    const float* __restrict__ res,
                                                    int M, int N, int K) {
  constexpr int NW = TN / 128;            // B-tile row multiple
  alignas(16) __shared__ unsigned short As[2][128 * 32];
  alignas(16) __shared__ unsigned short Bs[2][128 * NW * 32];
  const int t  = threadIdx.x;
  const int w  = t >> 6;
  const int l  = t & 63;
  const int wr = w >> 1, wc = w & 1;
  const int lr = l & 15, lk = l >> 4;

  const unsigned bid = blockIdx.y * gridDim.x + blockIdx.x;
  const unsigned cpx = (gridDim.x * gridDim.y) >> 3;
  const unsigned sw  = (bid & 7) * cpx + (bid >> 3);
  const int m0 = (int)(sw / gridDim.x) * 128;
  const int n0 = (int)(sw % gridDim.x) * TN;

  const int srow = t >> 2;                    // 0..63 (row within 64-row half)
  const int sgr  = (t & 3) ^ (srow & 3);      // pre-swizzled source granule

  auto stage = [&](int buf, int k0) {
#pragma unroll
    for (int r = 0; r < 2; ++r) {
      const unsigned short* ga = A + (size_t)(m0 + r * 64 + srow) * K + k0 + 8 * sgr;
      __builtin_amdgcn_global_load_lds((__attribute__((address_space(1))) void*)ga,
                                       (__attribute__((address_space(3))) void*)(&As[buf][r * 2048 + w * 512]),
                                       16, 0, 0);
    }
#pragma unroll
    for (int r = 0; r < 2 * NW; ++r) {
      const unsigned short* gb = B + (size_t)(n0 + r * 64 + srow) * K + k0 + 8 * sgr;
      __builtin_amdgcn_global_load_lds((__attribute__((address_space(1))) void*)gb,
                                       (__attribute__((address_space(3))) void*)(&Bs[buf][r * 2048 + w * 512]),
                                       16, 0, 0);
    }
  };

  f32x4 acc[4][4 * NW] = {};

  stage(0, 0);
  const int nIt = K >> 5;
  for (int it = 0; it < nIt; ++it) {
    const int buf = it & 1;
    __syncthreads();                          // drains vmcnt -> buf ready; WAR-safe
    if (it + 1 < nIt) stage(buf ^ 1, (it + 1) << 5);

    bf16x8 af[4], bf[4 * NW];
#pragma unroll
    for (int m = 0; m < 4; ++m)
      af[m] = *reinterpret_cast<const bf16x8*>(
          &As[buf][(wr * 64 + m * 16 + lr) * 32 + 8 * (lk ^ (lr & 3))]);
#pragma unroll
    for (int n = 0; n < 4 * NW; ++n)
      bf[n] = *reinterpret_cast<const bf16x8*>(
          &Bs[buf][(wc * 64 * NW + n * 16 + lr) * 32 + 8 * (lk ^ (lr & 3))]);
#pragma unroll
    for (int m = 0; m < 4; ++m)
#pragma unroll
      for (int n = 0; n < 4 * NW; ++n)
        acc[m][n] = __builtin_amdgcn_mfma_f32_16x16x32_bf16(af[m], bf[n], acc[m][n], 0, 0, 0);
  }

#pragma unroll
  for (int m = 0; m < 4; ++m) {
#pragma unroll
    for (int n = 0; n < 4 * NW; ++n) {
#pragma unroll
      for (int r = 0; r < 4; ++r) {
        const size_t row = (size_t)(m0 + wr * 64 + m * 16 + lk * 4 + r);
        const size_t col = (size_t)(n0 + wc * 64 * NW + n * 16 + lr);
        const float a = acc[m][n][r];
        if constexpr (EPI == 0) {
          ((unsigned short*)Cv)[row * N + col] = f2bf(a);
        } else if constexpr (EPI == 1) {
          ((float*)Cv)[row * N + col] = a + res[row * N + col];
        } else if constexpr (EPI == 2) {
          // GELU, tanh/exp2 form: g = h - h/(exp2(h*(a1+b1*h^2))+1)
          const float h2 = a * a;
          const float e  = exp2f(a * (2.30221535f + 0.10295355f * h2));
          const float g  = a - a / (e + 1.0f);
          ((unsigned short*)Cv)[row * N + col] = f2bf(g);
        } else {
          const float sc = (col < DM) ? 0.18033688011f : 1.0f;  // 0.125*log2(e) on Q
          ((unsigned short*)Cv)[row * N + col] = f2bf(a * sc);
        }
      }
    }
  }
}

// ---------------- Flash causal attention (64-row folded q-pairs) ----------------
// grid (HEADS, 16 pairs, BATCH) = 1024 blocks, 4 waves. Pair p handles 64-row
// q-tiles (p, 31-p); wave w owns rows qt*64+16w..+15 of each set. blockIdx.x=h
// keeps all pair-blocks of one (b,h) on one XCD. Q pre-scaled by 0.125*log2e.
// ROUND-14 CHANGE: single per-wave P buffer (8 KB) TIME-SHARED by the two
// sets (P-store->PV serialized per set with compiler fences only -- each
// wave's P region is private, so no hardware barrier needed). V-fragments
// hoisted to registers once per tile (vf[2][4], +32 VGPR) so LDS read count
// is unchanged. LDS 48->40 KB => 4 blocks/CU (was 3); grid supplies 4/CU.
__global__ __launch_bounds__(256, 4) void k_attn(const unsigned short* __restrict__ QK,
                                                 const unsigned short* __restrict__ VT,
                                                 unsigned short* __restrict__ O) {
  const int h   = blockIdx.x;
  const int qtA = blockIdx.y;                 // 0..15
  const int qtB = 31 - qtA;                   // 31..16
  const int b   = blockIdx.z;
  const int t  = threadIdx.x, w = t >> 6, l = t & 63;
  const int lr = l & 15, lk = l >> 4;
  const size_t rowB = (size_t)b * SEQ;
  const int hoff  = h * DKH;
  const int qw2[2] = { qtA * 64 + 16 * w, qtB * 64 + 16 * w };

  alignas(16) __shared__ unsigned short Ks[2][64 * 64];  // 16 KB
  alignas(16) __shared__ unsigned short Vt[2][64 * 64];  // 16 KB
  alignas(16) __shared__ unsigned short Ps[4][16 * 64];  // 8 KB, per-wave, set-time-shared

  char* const KsB  = (char*)Ks;
  char* const VtB  = (char*)Vt;
  char* const PsWB = (char*)(Ps[w]);

  auto stage = [&](int buf, int kb2) {
#pragma unroll
    for (int half = 0; half < 2; ++half) {
      const int srow = w * 16 + half * 8 + (l >> 3);
      const int sgr  = (l & 7) ^ (srow & 7);   // pre-swizzled source granule
      const unsigned short* gk = QK + (size_t)(rowB + kb2 + srow) * KSTR + DM + hoff + 8 * sgr;
      __builtin_amdgcn_global_load_lds((__attribute__((address_space(1))) void*)gk,
                                       (__attribute__((address_space(3))) void*)(KsB + buf * 8192 + w * 2048 + half * 1024),
                                       16, 0, 0);
      const unsigned short* gv = VT + (size_t)(hoff + srow) * NROWS + rowB + kb2 + 8 * sgr;
      __builtin_amdgcn_global_load_lds((__attribute__((address_space(1))) void*)gv,
                                       (__attribute__((address_space(3))) void*)(VtB + buf * 8192 + w * 2048 + half * 1024),
                                       16, 0, 0);
    }
  };

  bf16x8 qf[2][2];
#pragma unroll
  for (int s = 0; s < 2; ++s)
#pragma unroll
    for (int kk = 0; kk < 2; ++kk)
      qf[s][kk] = *reinterpret_cast<const bf16x8*>(
          QK + (rowB + qw2[s] + lr) * KSTR + hoff + 32 * kk + 8 * lk);

  f32x4 oacc[2][4] = {};
  float mrun[2] = {-1e30f, -1e30f};
  float lrun[2] = {0.0f, 0.0f};

  const int ktmax = qtB;
  stage(0, 0);
  for (int kt = 0; kt <= ktmax; ++kt) {
    const int kbase = kt * 64;
    const int cur   = kt & 1;
    __syncthreads();
    if (kt < ktmax) stage(cur ^ 1, kbase + 64);
    const char* Kc = KsB + cur * 8192;
    const char* Vc = VtB + cur * 8192;

    const bool act[2] = { kbase <= qw2[0] + 15, kbase <= qw2[1] + 15 };

    // ---- QK^T both sets: S^T[k][q]; K-fragments loaded once ----
    f32x4 sacc[2][4] = {};
#pragma unroll
    for (int tt = 0; tt < 4; ++tt) {
      bf16x8 kf0 = *reinterpret_cast<const bf16x8*>(Kc + (16 * tt + lr) * 128 + 16 * ((lk + 0) ^ (lr & 7)));
      bf16x8 kf1 = *reinterpret_cast<const bf16x8*>(Kc + (16 * tt + lr) * 128 + 16 * ((lk + 4) ^ (lr & 7)));
#pragma unroll
      for (int s = 0; s < 2; ++s) {
        if (!act[s]) continue;
        sacc[s][tt] = __builtin_amdgcn_mfma_f32_16x16x32_bf16(kf0, qf[s][0], sacc[s][tt], 0, 0, 0);
        sacc[s][tt] = __builtin_amdgcn_mfma_f32_16x16x32_bf16(kf1, qf[s][1], sacc[s][tt], 0, 0, 0);
      }
    }

    // ---- V-fragments for the whole tile (held in regs, used by both sets) ----
    bf16x8 vf[2][4];
#pragma unroll
    for (int kk = 0; kk < 2; ++kk)
#pragma unroll
      for (int dn = 0; dn < 4; ++dn)
        vf[kk][dn] = *reinterpret_cast<const bf16x8*>(
            Vc + (16 * dn + lr) * 128 + 16 * ((4 * kk + lk) ^ (lr & 7)));

    // ---- per set: softmax -> P-store -> PV (single per-wave P buffer) ----
#pragma unroll
    for (int s = 0; s < 2; ++s) {
      if (!act[s]) continue;
      const int qw = qw2[s];
      const int qg = qw + lr;
      float sv[4][4];
      if (kbase + 63 > qw) {
#pragma unroll
        for (int tt = 0; tt < 4; ++tt)
#pragma unroll
          for (int r = 0; r < 4; ++r) {
            const int kg = kbase + 16 * tt + 4 * lk + r;
            sv[tt][r] = (kg > qg) ? -1e30f : sacc[s][tt][r];
          }
      } else {
#pragma unroll
        for (int tt = 0; tt < 4; ++tt)
#pragma unroll
          for (int r = 0; r < 4; ++r) sv[tt][r] = sacc[s][tt][r];
      }
      float tm = sv[0][0];
#pragma unroll
      for (int tt = 0; tt < 4; ++tt)
#pragma unroll
        for (int r = 0; r < 4; ++r) tm = fmaxf(tm, sv[tt][r]);
      tm = fmaxf(tm, __shfl_xor(tm, 16));
      tm = fmaxf(tm, __shfl_xor(tm, 32));
      float mref = mrun[s];
      if (__any(tm > mref + 8.0f)) {            // defer-max
        const float mnew  = fmaxf(mref, tm);
        const float alpha = exp2f(mref - mnew);
#pragma unroll
        for (int r = 0; r < 4; ++r) {
          const float ar = __shfl(alpha, 4 * lk + r);
#pragma unroll
          for (int dn = 0; dn < 4; ++dn) oacc[s][dn][r] *= ar;
        }
        lrun[s] *= alpha;
        mrun[s] = mnew;
        mref = mnew;
      }
      float ts = 0.0f;
      unsigned short pb[4][4];
#pragma unroll
      for (int tt = 0; tt < 4; ++tt)
#pragma unroll
        for (int r = 0; r < 4; ++r) {
          const float p = exp2f(sv[tt][r] - mref);   // bounded by 2^8
          ts += p;
          pb[tt][r] = __builtin_bit_cast(unsigned short, static_cast<__bf16>(p));
        }
      ts += __shfl_xor(ts, 16);
      ts += __shfl_xor(ts, 32);
      lrun[s] += ts;
#pragma unroll
      for (int tt = 0; tt < 4; ++tt) {
        u16x4 pw = {pb[tt][0], pb[tt][1], pb[tt][2], pb[tt][3]};
        *reinterpret_cast<u16x4*>(
            PsWB + lr * 128 + ((32 * tt + 8 * lk) ^ (16 * (lr & 7)))) = pw;
      }

      // order this set's P stores before the typed re-read (TBAA-distinct)
      asm volatile("" ::: "memory");

#pragma unroll
      for (int kk = 0; kk < 2; ++kk) {
        bf16x8 pa = *reinterpret_cast<const bf16x8*>(
            PsWB + lr * 128 + ((64 * kk + 16 * lk) ^ (16 * (lr & 7))));
#pragma unroll
        for (int dn = 0; dn < 4; ++dn)
          oacc[s][dn] = __builtin_amdgcn_mfma_f32_16x16x32_bf16(pa, vf[kk][dn], oacc[s][dn], 0, 0, 0);
      }

      // order this set's P reads before the next set's / next tile's P stores (WAR)
      asm volatile("" ::: "memory");
    }
  }

#pragma unroll
  for (int s = 0; s < 2; ++s)
#pragma unroll
    for (int r = 0; r < 4; ++r) {
      const float li = 1.0f / __shfl(lrun[s], 4 * lk + r);
      const size_t row = rowB + qw2[s] + 4 * lk + r;
#pragma unroll
      for (int dn = 0; dn < 4; ++dn)
        O[row * DM + hoff + 16 * dn + lr] = f2bf(oacc[s][dn][r] * li);
    }
}

// ---------------- launch ----------------
extern "C" void kernel_launch(void* const* d_in, const int* in_sizes, int n_in,
                              void* d_out, int out_size, void* d_ws, size_t ws_size,
                              hipStream_t stream) {
  const float* x   = (const float*)d_in[0];
  const float* ln1 = (const float*)d_in[1];
  const float* ln2 = (const float*)d_in[2];
  const float* wq  = (const float*)d_in[3];
  const float* wk  = (const float*)d_in[4];
  const float* wv  = (const float*)d_in[5];
  const float* wo  = (const float*)d_in[6];
  const float* w1  = (const float*)d_in[7];
  const float* w2  = (const float*)d_in[8];

  char* ws = (char*)d_ws;
  size_t off = 0;
  auto take = [&](size_t bytes) { void* p = ws + off; off += bytes; return p; };
  unsigned short* wqkb = (unsigned short*)take((size_t)2 * DM * DM * 2);   // 4 MB (Q,K fused)
  unsigned short* wvb  = (unsigned short*)take((size_t)DM * DM * 2);       // 2 MB
  unsigned short* wob  = (unsigned short*)take((size_t)DM * DM * 2);       // 2 MB
  unsigned short* w1b  = (unsigned short*)take((size_t)DFF * DM * 2);      // 8 MB
  unsigned short* w2b  = (unsigned short*)take((size_t)DM * DFF * 2);      // 8 MB
  unsigned short* qk   = (unsigned short*)take((size_t)NROWS * 2 * DM * 2); // 32 MB
  unsigned short* xn   = (unsigned short*)take((size_t)NROWS * DM * 2);    // 16 MB (ln1 out, reused attn-out)
  unsigned short* vtb  = (unsigned short*)take((size_t)DM * NROWS * 2);    // 16 MB V^T [DM][NROWS]
  float*          yb   = (float*)take((size_t)NROWS * DM * 4);             // 32 MB fp32 residual
  unsigned short* hb   = (unsigned short*)take((size_t)NROWS * DFF * 2);   // 64 MB
  unsigned short* yn   = qk;   // ln2 out aliases qk (dead after attn)

  auto cvt = [&](const float* src, unsigned short* dst, size_t n) {
    int n4 = (int)(n / 4);
    k_f2bf<<<dim3((n4 + 255) / 256), dim3(256), 0, stream>>>(src, dst, n4);
  };
  cvt(wq, wqkb, (size_t)DM * DM);
  cvt(wk, wqkb + (size_t)DM * DM, (size_t)DM * DM);
  cvt(wv, wvb, (size_t)DM * DM);
  cvt(wo, wob, (size_t)DM * DM);
  cvt(w1, w1b, (size_t)DFF * DM);
  cvt(w2, w2b, (size_t)DM * DFF);

  k_rmsnorm<<<dim3(NROWS), dim3(256), 0, stream>>>(x, ln1, xn);

  // fused QK projection (EPI3: Q columns pre-scaled), 128x256 tile
  k_gemm_nt<3, 256><<<dim3(2 * DM / 256, NROWS / 128), dim3(256), 0, stream>>>(
      xn, wqkb, qk, nullptr, NROWS, 2 * DM, DM);

  // V^T directly: VT[DM][NROWS] = wv @ xn^T (operands swapped), 128x128 tile
  k_gemm_nt<0, 128><<<dim3(NROWS / 128, DM / 128), dim3(256), 0, stream>>>(
      wvb, xn, vtb, nullptr, DM, NROWS, DM);

  k_attn<<<dim3(HEADS, 16, BATCH), dim3(256), 0, stream>>>(qk, vtb, xn);

  k_gemm_nt<1, 128><<<dim3(DM / 128, NROWS / 128), dim3(256), 0, stream>>>(
      xn, wob, yb, x, NROWS, DM, DM);

  k_rmsnorm<<<dim3(NROWS), dim3(256), 0, stream>>>(yb, ln2, yn);

  // FFN1: 128x256 tile (grid 16x64 = 1024 blocks)
  k_gemm_nt<2, 256><<<dim3(DFF / 256, NROWS / 128), dim3(256), 0, stream>>>(
      yn, w1b, hb, nullptr, NROWS, DFF, DM);
  k_gemm_nt<1, 128><<<dim3(DM / 128, NROWS / 128), dim3(256), 0, stream>>>(
      hb, w2b, (float*)d_out, yb, NROWS, DM, DFF);
}

// Round 15
// 418.900 us; speedup vs baseline: 1.2644x; 1.2644x over previous
//
#include <hip/hip_runtime.h>

#define DM    1024
#define DFF   4096
#define SEQ   2048
#define BATCH 4
#define NROWS (BATCH * SEQ)   // 8192
#define HEADS 16
#define DKH   64
#define KSTR  (2 * DM)        // fused QK row stride

typedef __attribute__((ext_vector_type(4))) float          f32x4;
typedef __attribute__((ext_vector_type(8))) __bf16         bf16x8;
typedef __attribute__((ext_vector_type(8))) unsigned short u16x8;
typedef __attribute__((ext_vector_type(4))) unsigned short u16x4;

static __device__ __forceinline__ unsigned short f2bf(float f) {
  unsigned u = __builtin_bit_cast(unsigned, f);
  u += 0x7fffu + ((u >> 16) & 1u);   // round-to-nearest-even
  return (unsigned short)(u >> 16);
}

// ---------------- fp32 -> bf16 weight conversion ----------------
__global__ void k_f2bf(const float* __restrict__ in, unsigned short* __restrict__ out, int n4) {
  int i = blockIdx.x * blockDim.x + threadIdx.x;
  if (i >= n4) return;
  float4 v = reinterpret_cast<const float4*>(in)[i];
  ushort4 o;
  o.x = f2bf(v.x); o.y = f2bf(v.y); o.z = f2bf(v.z); o.w = f2bf(v.w);
  reinterpret_cast<ushort4*>(out)[i] = o;
}

// ---------------- RMSNorm: fp32 in -> bf16 out ----------------
__global__ __launch_bounds__(256) void k_rmsnorm(const float* __restrict__ x,
                                                 const float* __restrict__ w,
                                                 unsigned short* __restrict__ out) {
  const int row = blockIdx.x;
  const float4 v = reinterpret_cast<const float4*>(x + (size_t)row * DM)[threadIdx.x];
  float ss = v.x * v.x + v.y * v.y + v.z * v.z + v.w * v.w;
#pragma unroll
  for (int off = 32; off > 0; off >>= 1) ss += __shfl_down(ss, off);
  __shared__ float red[4];
  if ((threadIdx.x & 63) == 0) red[threadIdx.x >> 6] = ss;
  __syncthreads();
  const float tot  = red[0] + red[1] + red[2] + red[3];
  const float rden = rsqrtf(tot * (1.0f / DM) + 1e-5f);
  const float4 wv = reinterpret_cast<const float4*>(w)[threadIdx.x];
  ushort4 o;
  o.x = f2bf(v.x * wv.x * rden);
  o.y = f2bf(v.y * wv.y * rden);
  o.z = f2bf(v.z * wv.z * rden);
  o.w = f2bf(v.w * wv.w * rden);
  reinterpret_cast<ushort4*>(out + (size_t)row * DM)[threadIdx.x] = o;
}

// ---------------- NT GEMM: C(MxN) = A(MxK,bf16) * B(NxK,bf16)^T ----------------
// Round-9-proven structure, templated on tile width TN (128 or 256).
// 128xTN tile, 4 waves (2x2), wave tile 64 x TN/2; double-buffered 2-phase
// K-loop; row-major [rows][32] LDS with COALESCED staging (4 lanes per 64B
// row) + granule XOR. Round-10 lesson: do NOT trade staging coalescing for
// LDS-conflict-freedom (lost 40%). TN=256 cuts LDS bytes/FLOP by 1.33x;
// use only when grid >= 2 blocks/CU. EPI: 0 bf16, 1 fp32+res, 2 gelu,
// 3 bf16 with Q-half pre-scaled by 0.125*log2e.
template <int EPI, int TN>
__global__ __launch_bounds__(256, 2) void k_gemm_nt(const unsigned short* __restrict__ A,
                                                    const unsigned short* __restrict__ B,
                                                    void* __restrict__ Cv,
                                                    const float* __restrict__ res,
                                                    int M, int N, int K) {
  constexpr int NW = TN / 128;            // B-tile row multiple
  alignas(16) __shared__ unsigned short As[2][128 * 32];
  alignas(16) __shared__ unsigned short Bs[2][128 * NW * 32];
  const int t  = threadIdx.x;
  const int w  = t >> 6;
  const int l  = t & 63;
  const int wr = w >> 1, wc = w & 1;
  const int lr = l & 15, lk = l >> 4;

  const unsigned bid = blockIdx.y * gridDim.x + blockIdx.x;
  const unsigned cpx = (gridDim.x * gridDim.y) >> 3;
  const unsigned sw  = (bid & 7) * cpx + (bid >> 3);
  const int m0 = (int)(sw / gridDim.x) * 128;
  const int n0 = (int)(sw % gridDim.x) * TN;

  const int srow = t >> 2;                    // 0..63 (row within 64-row half)
  const int sgr  = (t & 3) ^ (srow & 3);      // pre-swizzled source granule

  auto stage = [&](int buf, int k0) {
#pragma unroll
    for (int r = 0; r < 2; ++r) {
      const unsigned short* ga = A + (size_t)(m0 + r * 64 + srow) * K + k0 + 8 * sgr;
      __builtin_amdgcn_global_load_lds((__attribute__((address_space(1))) void*)ga,
                                       (__attribute__((address_space(3))) void*)(&As[buf][r * 2048 + w * 512]),
                                       16, 0, 0);
    }
#pragma unroll
    for (int r = 0; r < 2 * NW; ++r) {
      const unsigned short* gb = B + (size_t)(n0 + r * 64 + srow) * K + k0 + 8 * sgr;
      __builtin_amdgcn_global_load_lds((__attribute__((address_space(1))) void*)gb,
                                       (__attribute__((address_space(3))) void*)(&Bs[buf][r * 2048 + w * 512]),
                                       16, 0, 0);
    }
  };

  f32x4 acc[4][4 * NW] = {};

  stage(0, 0);
  const int nIt = K >> 5;
  for (int it = 0; it < nIt; ++it) {
    const int buf = it & 1;
    __syncthreads();                          // drains vmcnt -> buf ready; WAR-safe
    if (it + 1 < nIt) stage(buf ^ 1, (it + 1) << 5);

    bf16x8 af[4], bf[4 * NW];
#pragma unroll
    for (int m = 0; m < 4; ++m)
      af[m] = *reinterpret_cast<const bf16x8*>(
          &As[buf][(wr * 64 + m * 16 + lr) * 32 + 8 * (lk ^ (lr & 3))]);
#pragma unroll
    for (int n = 0; n < 4 * NW; ++n)
      bf[n] = *reinterpret_cast<const bf16x8*>(
          &Bs[buf][(wc * 64 * NW + n * 16 + lr) * 32 + 8 * (lk ^ (lr & 3))]);
#pragma unroll
    for (int m = 0; m < 4; ++m)
#pragma unroll
      for (int n = 0; n < 4 * NW; ++n)
        acc[m][n] = __builtin_amdgcn_mfma_f32_16x16x32_bf16(af[m], bf[n], acc[m][n], 0, 0, 0);
  }

#pragma unroll
  for (int m = 0; m < 4; ++m) {
#pragma unroll
    for (int n = 0; n < 4 * NW; ++n) {
#pragma unroll
      for (int r = 0; r < 4; ++r) {
        const size_t row = (size_t)(m0 + wr * 64 + m * 16 + lk * 4 + r);
        const size_t col = (size_t)(n0 + wc * 64 * NW + n * 16 + lr);
        const float a = acc[m][n][r];
        if constexpr (EPI == 0) {
          ((unsigned short*)Cv)[row * N + col] = f2bf(a);
        } else if constexpr (EPI == 1) {
          ((float*)Cv)[row * N + col] = a + res[row * N + col];
        } else if constexpr (EPI == 2) {
          // GELU, tanh/exp2 form: g = h - h/(exp2(h*(a1+b1*h^2))+1)
          const float h2 = a * a;
          const float e  = exp2f(a * (2.30221535f + 0.10295355f * h2));
          const float g  = a - a / (e + 1.0f);
          ((unsigned short*)Cv)[row * N + col] = f2bf(g);
        } else {
          const float sc = (col < DM) ? 0.18033688011f : 1.0f;  // 0.125*log2(e) on Q
          ((unsigned short*)Cv)[row * N + col] = f2bf(a * sc);
        }
      }
    }
  }
}

// ---------------- Flash causal attention (64-row folded q-pairs) ----------------
// ROUND-13 PROVEN VERSION (111us, 68 VGPR, 48KB LDS, 3 blocks/CU).
// grid (HEADS, 16 pairs, BATCH) = 1024 blocks, 4 waves. Pair p handles 64-row
// q-tiles (p, 31-p); wave w owns rows qt*64+16w..+15 of each set. blockIdx.x=h
// keeps all pair-blocks of one (b,h) on one XCD. Q pre-scaled by 0.125*log2e.
// ROUND-14 LESSON: squeezing LDS to 40KB via a time-shared P buffer + hoisted
// V-fragments + launch_bounds(256,4) caused REGISTER SPILLS (WRITE_SIZE
// 16->48MB scratch traffic, 111->198us). The r13 point (68 VGPR, Ps[2],
// inline vf, bounds(256,3)) is the local optimum; don't trade registers or
// LDS bytes for occupancy here without resource-usage verification.
__global__ __launch_bounds__(256, 3) void k_attn(const unsigned short* __restrict__ QK,
                                                 const unsigned short* __restrict__ VT,
                                                 unsigned short* __restrict__ O) {
  const int h   = blockIdx.x;
  const int qtA = blockIdx.y;                 // 0..15
  const int qtB = 31 - qtA;                   // 31..16
  const int b   = blockIdx.z;
  const int t  = threadIdx.x, w = t >> 6, l = t & 63;
  const int lr = l & 15, lk = l >> 4;
  const size_t rowB = (size_t)b * SEQ;
  const int hoff  = h * DKH;
  const int qw2[2] = { qtA * 64 + 16 * w, qtB * 64 + 16 * w };

  alignas(16) __shared__ unsigned short Ks[2][64 * 64];    // 16 KB
  alignas(16) __shared__ unsigned short Vt[2][64 * 64];    // 16 KB
  alignas(16) __shared__ unsigned short Ps[2][4][16 * 64]; // 16 KB

  char* const KsB = (char*)Ks;
  char* const VtB = (char*)Vt;

  auto stage = [&](int buf, int kb2) {
#pragma unroll
    for (int half = 0; half < 2; ++half) {
      const int srow = w * 16 + half * 8 + (l >> 3);
      const int sgr  = (l & 7) ^ (srow & 7);   // pre-swizzled source granule
      const unsigned short* gk = QK + (size_t)(rowB + kb2 + srow) * KSTR + DM + hoff + 8 * sgr;
      __builtin_amdgcn_global_load_lds((__attribute__((address_space(1))) void*)gk,
                                       (__attribute__((address_space(3))) void*)(KsB + buf * 8192 + w * 2048 + half * 1024),
                                       16, 0, 0);
      const unsigned short* gv = VT + (size_t)(hoff + srow) * NROWS + rowB + kb2 + 8 * sgr;
      __builtin_amdgcn_global_load_lds((__attribute__((address_space(1))) void*)gv,
                                       (__attribute__((address_space(3))) void*)(VtB + buf * 8192 + w * 2048 + half * 1024),
                                       16, 0, 0);
    }
  };

  bf16x8 qf[2][2];
#pragma unroll
  for (int s = 0; s < 2; ++s)
#pragma unroll
    for (int kk = 0; kk < 2; ++kk)
      qf[s][kk] = *reinterpret_cast<const bf16x8*>(
          QK + (rowB + qw2[s] + lr) * KSTR + hoff + 32 * kk + 8 * lk);

  f32x4 oacc[2][4] = {};
  float mrun[2] = {-1e30f, -1e30f};
  float lrun[2] = {0.0f, 0.0f};

  const int ktmax = qtB;
  stage(0, 0);
  for (int kt = 0; kt <= ktmax; ++kt) {
    const int kbase = kt * 64;
    const int cur   = kt & 1;
    __syncthreads();
    if (kt < ktmax) stage(cur ^ 1, kbase + 64);
    const char* Kc = KsB + cur * 8192;
    const char* Vc = VtB + cur * 8192;

    const bool act[2] = { kbase <= qw2[0] + 15, kbase <= qw2[1] + 15 };

    f32x4 sacc[2][4] = {};
#pragma unroll
    for (int tt = 0; tt < 4; ++tt) {
      bf16x8 kf0 = *reinterpret_cast<const bf16x8*>(Kc + (16 * tt + lr) * 128 + 16 * ((lk + 0) ^ (lr & 7)));
      bf16x8 kf1 = *reinterpret_cast<const bf16x8*>(Kc + (16 * tt + lr) * 128 + 16 * ((lk + 4) ^ (lr & 7)));
#pragma unroll
      for (int s = 0; s < 2; ++s) {
        if (!act[s]) continue;
        sacc[s][tt] = __builtin_amdgcn_mfma_f32_16x16x32_bf16(kf0, qf[s][0], sacc[s][tt], 0, 0, 0);
        sacc[s][tt] = __builtin_amdgcn_mfma_f32_16x16x32_bf16(kf1, qf[s][1], sacc[s][tt], 0, 0, 0);
      }
    }

#pragma unroll
    for (int s = 0; s < 2; ++s) {
      if (!act[s]) continue;
      const int qw = qw2[s];
      char* const PsSB = (char*)(Ps[s][w]);
      const int qg = qw + lr;
      float sv[4][4];
      if (kbase + 63 > qw) {
#pragma unroll
        for (int tt = 0; tt < 4; ++tt)
#pragma unroll
          for (int r = 0; r < 4; ++r) {
            const int kg = kbase + 16 * tt + 4 * lk + r;
            sv[tt][r] = (kg > qg) ? -1e30f : sacc[s][tt][r];
          }
      } else {
#pragma unroll
        for (int tt = 0; tt < 4; ++tt)
#pragma unroll
          for (int r = 0; r < 4; ++r) sv[tt][r] = sacc[s][tt][r];
      }
      float tm = sv[0][0];
#pragma unroll
      for (int tt = 0; tt < 4; ++tt)
#pragma unroll
        for (int r = 0; r < 4; ++r) tm = fmaxf(tm, sv[tt][r]);
      tm = fmaxf(tm, __shfl_xor(tm, 16));
      tm = fmaxf(tm, __shfl_xor(tm, 32));
      float mref = mrun[s];
      if (__any(tm > mref + 8.0f)) {            // defer-max
        const float mnew  = fmaxf(mref, tm);
        const float alpha = exp2f(mref - mnew);
#pragma unroll
        for (int r = 0; r < 4; ++r) {
          const float ar = __shfl(alpha, 4 * lk + r);
#pragma unroll
          for (int dn = 0; dn < 4; ++dn) oacc[s][dn][r] *= ar;
        }
        lrun[s] *= alpha;
        mrun[s] = mnew;
        mref = mnew;
      }
      float ts = 0.0f;
      unsigned short pb[4][4];
#pragma unroll
      for (int tt = 0; tt < 4; ++tt)
#pragma unroll
        for (int r = 0; r < 4; ++r) {
          const float p = exp2f(sv[tt][r] - mref);   // bounded by 2^8
          ts += p;
          pb[tt][r] = __builtin_bit_cast(unsigned short, static_cast<__bf16>(p));
        }
      ts += __shfl_xor(ts, 16);
      ts += __shfl_xor(ts, 32);
      lrun[s] += ts;
#pragma unroll
      for (int tt = 0; tt < 4; ++tt) {
        u16x4 pw = {pb[tt][0], pb[tt][1], pb[tt][2], pb[tt][3]};
        *reinterpret_cast<u16x4*>(
            PsSB + lr * 128 + ((32 * tt + 8 * lk) ^ (16 * (lr & 7)))) = pw;
      }
    }

    // order P stores before the TBAA-distinct typed re-reads below
    asm volatile("" ::: "memory");

#pragma unroll
    for (int kk = 0; kk < 2; ++kk) {
      bf16x8 vf[4];
#pragma unroll
      for (int dn = 0; dn < 4; ++dn)
        vf[dn] = *reinterpret_cast<const bf16x8*>(
            Vc + (16 * dn + lr) * 128 + 16 * ((4 * kk + lk) ^ (lr & 7)));
#pragma unroll
      for (int s = 0; s < 2; ++s) {
        if (!act[s]) continue;
        char* const PsSB = (char*)(Ps[s][w]);
        bf16x8 pa = *reinterpret_cast<const bf16x8*>(
            PsSB + lr * 128 + ((64 * kk + 16 * lk) ^ (16 * (lr & 7))));
#pragma unroll
        for (int dn = 0; dn < 4; ++dn)
          oacc[s][dn] = __builtin_amdgcn_mfma_f32_16x16x32_bf16(pa, vf[dn], oacc[s][dn], 0, 0, 0);
      }
    }

    // order PV's P reads before next iteration's P stores (same-wave WAR on Ps)
    asm volatile("" ::: "memory");
  }

#pragma unroll
  for (int s = 0; s < 2; ++s)
#pragma unroll
    for (int r = 0; r < 4; ++r) {
      const float li = 1.0f / __shfl(lrun[s], 4 * lk + r);
      const size_t row = rowB + qw2[s] + 4 * lk + r;
#pragma unroll
      for (int dn = 0; dn < 4; ++dn)
        O[row * DM + hoff + 16 * dn + lr] = f2bf(oacc[s][dn][r] * li);
    }
}

// ---------------- launch ----------------
extern "C" void kernel_launch(void* const* d_in, const int* in_sizes, int n_in,
                              void* d_out, int out_size, void* d_ws, size_t ws_size,
                              hipStream_t stream) {
  const float* x   = (const float*)d_in[0];
  const float* ln1 = (const float*)d_in[1];
  const float* ln2 = (const float*)d_in[2];
  const float* wq  = (const float*)d_in[3];
  const float* wk  = (const float*)d_in[4];
  const float* wv  = (const float*)d_in[5];
  const float* wo  = (const float*)d_in[6];
  const float* w1  = (const float*)d_in[7];
  const float* w2  = (const float*)d_in[8];

  char* ws = (char*)d_ws;
  size_t off = 0;
  auto take = [&](size_t bytes) { void* p = ws + off; off += bytes; return p; };
  unsigned short* wqkb = (unsigned short*)take((size_t)2 * DM * DM * 2);   // 4 MB (Q,K fused)
  unsigned short* wvb  = (unsigned short*)take((size_t)DM * DM * 2);       // 2 MB
  unsigned short* wob  = (unsigned short*)take((size_t)DM * DM * 2);       // 2 MB
  unsigned short* w1b  = (unsigned short*)take((size_t)DFF * DM * 2);      // 8 MB
  unsigned short* w2b  = (unsigned short*)take((size_t)DM * DFF * 2);      // 8 MB
  unsigned short* qk   = (unsigned short*)take((size_t)NROWS * 2 * DM * 2); // 32 MB
  unsigned short* xn   = (unsigned short*)take((size_t)NROWS * DM * 2);    // 16 MB (ln1 out, reused attn-out)
  unsigned short* vtb  = (unsigned short*)take((size_t)DM * NROWS * 2);    // 16 MB V^T [DM][NROWS]
  float*          yb   = (float*)take((size_t)NROWS * DM * 4);             // 32 MB fp32 residual
  unsigned short* hb   = (unsigned short*)take((size_t)NROWS * DFF * 2);   // 64 MB
  unsigned short* yn   = qk;   // ln2 out aliases qk (dead after attn)

  auto cvt = [&](const float* src, unsigned short* dst, size_t n) {
    int n4 = (int)(n / 4);
    k_f2bf<<<dim3((n4 + 255) / 256), dim3(256), 0, stream>>>(src, dst, n4);
  };
  cvt(wq, wqkb, (size_t)DM * DM);
  cvt(wk, wqkb + (size_t)DM * DM, (size_t)DM * DM);
  cvt(wv, wvb, (size_t)DM * DM);
  cvt(wo, wob, (size_t)DM * DM);
  cvt(w1, w1b, (size_t)DFF * DM);
  cvt(w2, w2b, (size_t)DM * DFF);

  k_rmsnorm<<<dim3(NROWS), dim3(256), 0, stream>>>(x, ln1, xn);

  // fused QK projection (EPI3: Q columns pre-scaled), 128x256 tile
  k_gemm_nt<3, 256><<<dim3(2 * DM / 256, NROWS / 128), dim3(256), 0, stream>>>(
      xn, wqkb, qk, nullptr, NROWS, 2 * DM, DM);

  // V^T directly: VT[DM][NROWS] = wv @ xn^T (operands swapped), 128x128 tile
  k_gemm_nt<0, 128><<<dim3(NROWS / 128, DM / 128), dim3(256), 0, stream>>>(
      wvb, xn, vtb, nullptr, DM, NROWS, DM);

  k_attn<<<dim3(HEADS, 16, BATCH), dim3(256), 0, stream>>>(qk, vtb, xn);

  k_gemm_nt<1, 128><<<dim3(DM / 128, NROWS / 128), dim3(256), 0, stream>>>(
      xn, wob, yb, x, NROWS, DM, DM);

  k_rmsnorm<<<dim3(NROWS), dim3(256), 0, stream>>>(yb, ln2, yn);

  // FFN1: 128x256 tile (grid 16x64 = 1024 blocks)
  k_gemm_nt<2, 256><<<dim3(DFF / 256, NROWS / 128), dim3(256), 0, stream>>>(
      yn, w1b, hb, nullptr, NROWS, DFF, DM);
  k_gemm_nt<1, 128><<<dim3(DM / 128, NROWS / 128), dim3(256), 0, stream>>>(
      hb, w2b, (float*)d_out, yb, NROWS, DM, DFF);
}

// Round 16
// 391.005 us; speedup vs baseline: 1.3546x; 1.0713x over previous
//
#include <hip/hip_runtime.h>

#define DM    1024
#define DFF   4096
#define SEQ   2048
#define BATCH 4
#define NROWS (BATCH * SEQ)   // 8192
#define HEADS 16
#define DKH   64
#define KSTR  (2 * DM)        // fused QK row stride

typedef __attribute__((ext_vector_type(4))) float          f32x4;
typedef __attribute__((ext_vector_type(8))) __bf16         bf16x8;
typedef __attribute__((ext_vector_type(8))) unsigned short u16x8;
typedef __attribute__((ext_vector_type(4))) unsigned short u16x4;

static __device__ __forceinline__ unsigned short f2bf(float f) {
  unsigned u = __builtin_bit_cast(unsigned, f);
  u += 0x7fffu + ((u >> 16) & 1u);   // round-to-nearest-even
  return (unsigned short)(u >> 16);
}

// ---------------- fp32 -> bf16 weight conversion ----------------
__global__ void k_f2bf(const float* __restrict__ in, unsigned short* __restrict__ out, int n4) {
  int i = blockIdx.x * blockDim.x + threadIdx.x;
  if (i >= n4) return;
  float4 v = reinterpret_cast<const float4*>(in)[i];
  ushort4 o;
  o.x = f2bf(v.x); o.y = f2bf(v.y); o.z = f2bf(v.z); o.w = f2bf(v.w);
  reinterpret_cast<ushort4*>(out)[i] = o;
}

// ---------------- RMSNorm: fp32 in -> bf16 out ----------------
__global__ __launch_bounds__(256) void k_rmsnorm(const float* __restrict__ x,
                                                 const float* __restrict__ w,
                                                 unsigned short* __restrict__ out) {
  const int row = blockIdx.x;
  const float4 v = reinterpret_cast<const float4*>(x + (size_t)row * DM)[threadIdx.x];
  float ss = v.x * v.x + v.y * v.y + v.z * v.z + v.w * v.w;
#pragma unroll
  for (int off = 32; off > 0; off >>= 1) ss += __shfl_down(ss, off);
  __shared__ float red[4];
  if ((threadIdx.x & 63) == 0) red[threadIdx.x >> 6] = ss;
  __syncthreads();
  const float tot  = red[0] + red[1] + red[2] + red[3];
  const float rden = rsqrtf(tot * (1.0f / DM) + 1e-5f);
  const float4 wv = reinterpret_cast<const float4*>(w)[threadIdx.x];
  ushort4 o;
  o.x = f2bf(v.x * wv.x * rden);
  o.y = f2bf(v.y * wv.y * rden);
  o.z = f2bf(v.z * wv.z * rden);
  o.w = f2bf(v.w * wv.w * rden);
  reinterpret_cast<ushort4*>(out + (size_t)row * DM)[threadIdx.x] = o;
}

// ---------------- NT GEMM: C(MxN) = A(MxK,bf16) * B(NxK,bf16)^T ----------------
// Round-9-proven structure, templated on tile width TN (128/256) and K-step
// BK (32/64). 128xTN tile, 4 waves (2x2); double-buffered 2-phase K-loop;
// row-major LDS with COALESCED staging + granule XOR.
// Round-10 lesson: never trade staging coalescing for LDS-conflict-freedom.
// Round-13: TN=256 (use only when grid >= 2 blocks/CU) cut LDS bytes/FLOP.
// Round-16: BK=64 for TN=128 instances -- the 2-phase loop is BARRIER-STALL
// bound (m233: ~50%+ in vmcnt-drain+barrier); BK=64 halves barriers/FLOP.
// LDS 64KB still allows the 2 blocks/CU these grids supply; fragments are
// loaded per-kk (32 regs live) to stay under the 128-VGPR 2-wave cap (the
// r14 spill lesson). EPI: 0 bf16, 1 fp32+res, 2 gelu, 3 Q-prescale.
template <int EPI, int TN, int BK>
__global__ __launch_bounds__(256, 2) void k_gemm_nt(const unsigned short* __restrict__ A,
                                                    const unsigned short* __restrict__ B,
                                                    void* __restrict__ Cv,
                                                    const float* __restrict__ res,
                                                    int M, int N, int K) {
  constexpr int NW = TN / 128;            // B-tile row multiple
  alignas(16) __shared__ unsigned short As[2][128 * BK];
  alignas(16) __shared__ unsigned short Bs[2][128 * NW * BK];
  const int t  = threadIdx.x;
  const int w  = t >> 6;
  const int l  = t & 63;
  const int wr = w >> 1, wc = w & 1;
  const int lr = l & 15, lk = l >> 4;

  const unsigned bid = blockIdx.y * gridDim.x + blockIdx.x;
  const unsigned cpx = (gridDim.x * gridDim.y) >> 3;
  const unsigned sw  = (bid & 7) * cpx + (bid >> 3);
  const int m0 = (int)(sw / gridDim.x) * 128;
  const int n0 = (int)(sw % gridDim.x) * TN;

  auto stage = [&](int buf, int k0) {
    if constexpr (BK == 32) {
      const int srow = t >> 2;                  // 0..63, 4 lanes per 64B row
      const int sgr  = (t & 3) ^ (srow & 3);    // pre-swizzled source granule
#pragma unroll
      for (int r = 0; r < 2; ++r) {
        const unsigned short* ga = A + (size_t)(m0 + r * 64 + srow) * K + k0 + 8 * sgr;
        __builtin_amdgcn_global_load_lds((__attribute__((address_space(1))) void*)ga,
                                         (__attribute__((address_space(3))) void*)(&As[buf][r * 2048 + w * 512]),
                                         16, 0, 0);
      }
#pragma unroll
      for (int r = 0; r < 2 * NW; ++r) {
        const unsigned short* gb = B + (size_t)(n0 + r * 64 + srow) * K + k0 + 8 * sgr;
        __builtin_amdgcn_global_load_lds((__attribute__((address_space(1))) void*)gb,
                                         (__attribute__((address_space(3))) void*)(&Bs[buf][r * 2048 + w * 512]),
                                         16, 0, 0);
      }
    } else {
      // BK == 64 (TN==128): 128B rows, 8 lanes per row; 4 issues cover 128 rows
      const int srow8 = l >> 3;                 // row within wave's 8-row group
      const int g     = l & 7;
#pragma unroll
      for (int i = 0; i < 4; ++i) {
        const int row = i * 32 + w * 8 + srow8;
        const int sg  = g ^ (row & 7);          // pre-swizzled source granule
        const unsigned short* ga = A + (size_t)(m0 + row) * K + k0 + 8 * sg;
        __builtin_amdgcn_global_load_lds((__attribute__((address_space(1))) void*)ga,
                                         (__attribute__((address_space(3))) void*)(&As[buf][i * 2048 + w * 512]),
                                         16, 0, 0);
        const unsigned short* gb = B + (size_t)(n0 + row) * K + k0 + 8 * sg;
        __builtin_amdgcn_global_load_lds((__attribute__((address_space(1))) void*)gb,
                                         (__attribute__((address_space(3))) void*)(&Bs[buf][i * 2048 + w * 512]),
                                         16, 0, 0);
      }
    }
  };

  f32x4 acc[4][4 * NW] = {};

  stage(0, 0);
  const int nIt = K / BK;
  for (int it = 0; it < nIt; ++it) {
    const int buf = it & 1;
    __syncthreads();                          // drains vmcnt -> buf ready; WAR-safe
    if (it + 1 < nIt) stage(buf ^ 1, (it + 1) * BK);

    if constexpr (BK == 32) {
      bf16x8 af[4], bf[4 * NW];
#pragma unroll
      for (int m = 0; m < 4; ++m)
        af[m] = *reinterpret_cast<const bf16x8*>(
            &As[buf][(wr * 64 + m * 16 + lr) * 32 + 8 * (lk ^ (lr & 3))]);
#pragma unroll
      for (int n = 0; n < 4 * NW; ++n)
        bf[n] = *reinterpret_cast<const bf16x8*>(
            &Bs[buf][(wc * 64 * NW + n * 16 + lr) * 32 + 8 * (lk ^ (lr & 3))]);
#pragma unroll
      for (int m = 0; m < 4; ++m)
#pragma unroll
        for (int n = 0; n < 4 * NW; ++n)
          acc[m][n] = __builtin_amdgcn_mfma_f32_16x16x32_bf16(af[m], bf[n], acc[m][n], 0, 0, 0);
    } else {
      // BK == 64: two K=32 slices; load fragments per-slice to bound VGPR
#pragma unroll
      for (int kk = 0; kk < 2; ++kk) {
        bf16x8 af[4], bf[4];
#pragma unroll
        for (int m = 0; m < 4; ++m)
          af[m] = *reinterpret_cast<const bf16x8*>(
              &As[buf][(wr * 64 + m * 16 + lr) * 64 + 8 * ((4 * kk + lk) ^ (lr & 7))]);
#pragma unroll
        for (int n = 0; n < 4; ++n)
          bf[n] = *reinterpret_cast<const bf16x8*>(
              &Bs[buf][(wc * 64 + n * 16 + lr) * 64 + 8 * ((4 * kk + lk) ^ (lr & 7))]);
#pragma unroll
        for (int m = 0; m < 4; ++m)
#pragma unroll
          for (int n = 0; n < 4; ++n)
            acc[m][n] = __builtin_amdgcn_mfma_f32_16x16x32_bf16(af[m], bf[n], acc[m][n], 0, 0, 0);
      }
    }
  }

#pragma unroll
  for (int m = 0; m < 4; ++m) {
#pragma unroll
    for (int n = 0; n < 4 * NW; ++n) {
#pragma unroll
      for (int r = 0; r < 4; ++r) {
        const size_t row = (size_t)(m0 + wr * 64 + m * 16 + lk * 4 + r);
        const size_t col = (size_t)(n0 + wc * 64 * NW + n * 16 + lr);
        const float a = acc[m][n][r];
        if constexpr (EPI == 0) {
          ((unsigned short*)Cv)[row * N + col] = f2bf(a);
        } else if constexpr (EPI == 1) {
          ((float*)Cv)[row * N + col] = a + res[row * N + col];
        } else if constexpr (EPI == 2) {
          // GELU, tanh/exp2 form: g = h - h/(exp2(h*(a1+b1*h^2))+1)
          const float h2 = a * a;
          const float e  = exp2f(a * (2.30221535f + 0.10295355f * h2));
          const float g  = a - a / (e + 1.0f);
          ((unsigned short*)Cv)[row * N + col] = f2bf(g);
        } else {
          const float sc = (col < DM) ? 0.18033688011f : 1.0f;  // 0.125*log2(e) on Q
          ((unsigned short*)Cv)[row * N + col] = f2bf(a * sc);
        }
      }
    }
  }
}

// ---------------- Flash causal attention (64-row folded q-pairs) ----------------
// ROUND-13 PROVEN VERSION (111us, 68 VGPR, 48KB LDS, 3 blocks/CU).
// grid (HEADS, 16 pairs, BATCH) = 1024 blocks, 4 waves. Pair p handles 64-row
// q-tiles (p, 31-p); wave w owns rows qt*64+16w..+15 of each set. blockIdx.x=h
// keeps all pair-blocks of one (b,h) on one XCD. Q pre-scaled by 0.125*log2e.
// ROUND-14 LESSON: LDS squeeze + launch_bounds(256,4) caused register spills
// (WRITE_SIZE 16->48MB scratch, 111->198us). r13 point is the local optimum.
__global__ __launch_bounds__(256, 3) void k_attn(const unsigned short* __restrict__ QK,
                                                 const unsigned short* __restrict__ VT,
                                                 unsigned short* __restrict__ O) {
  const int h   = blockIdx.x;
  const int qtA = blockIdx.y;                 // 0..15
  const int qtB = 31 - qtA;                   // 31..16
  const int b   = blockIdx.z;
  const int t  = threadIdx.x, w = t >> 6, l = t & 63;
  const int lr = l & 15, lk = l >> 4;
  const size_t rowB = (size_t)b * SEQ;
  const int hoff  = h * DKH;
  const int qw2[2] = { qtA * 64 + 16 * w, qtB * 64 + 16 * w };

  alignas(16) __shared__ unsigned short Ks[2][64 * 64];    // 16 KB
  alignas(16) __shared__ unsigned short Vt[2][64 * 64];    // 16 KB
  alignas(16) __shared__ unsigned short Ps[2][4][16 * 64]; // 16 KB

  char* const KsB = (char*)Ks;
  char* const VtB = (char*)Vt;

  auto stage = [&](int buf, int kb2) {
#pragma unroll
    for (int half = 0; half < 2; ++half) {
      const int srow = w * 16 + half * 8 + (l >> 3);
      const int sgr  = (l & 7) ^ (srow & 7);   // pre-swizzled source granule
      const unsigned short* gk = QK + (size_t)(rowB + kb2 + srow) * KSTR + DM + hoff + 8 * sgr;
      __builtin_amdgcn_global_load_lds((__attribute__((address_space(1))) void*)gk,
                                       (__attribute__((address_space(3))) void*)(KsB + buf * 8192 + w * 2048 + half * 1024),
                                       16, 0, 0);
      const unsigned short* gv = VT + (size_t)(hoff + srow) * NROWS + rowB + kb2 + 8 * sgr;
      __builtin_amdgcn_global_load_lds((__attribute__((address_space(1))) void*)gv,
                                       (__attribute__((address_space(3))) void*)(VtB + buf * 8192 + w * 2048 + half * 1024),
                                       16, 0, 0);
    }
  };

  bf16x8 qf[2][2];
#pragma unroll
  for (int s = 0; s < 2; ++s)
#pragma unroll
    for (int kk = 0; kk < 2; ++kk)
      qf[s][kk] = *reinterpret_cast<const bf16x8*>(
          QK + (rowB + qw2[s] + lr) * KSTR + hoff + 32 * kk + 8 * lk);

  f32x4 oacc[2][4] = {};
  float mrun[2] = {-1e30f, -1e30f};
  float lrun[2] = {0.0f, 0.0f};

  const int ktmax = qtB;
  stage(0, 0);
  for (int kt = 0; kt <= ktmax; ++kt) {
    const int kbase = kt * 64;
    const int cur   = kt & 1;
    __syncthreads();
    if (kt < ktmax) stage(cur ^ 1, kbase + 64);
    const char* Kc = KsB + cur * 8192;
    const char* Vc = VtB + cur * 8192;

    const bool act[2] = { kbase <= qw2[0] + 15, kbase <= qw2[1] + 15 };

    f32x4 sacc[2][4] = {};
#pragma unroll
    for (int tt = 0; tt < 4; ++tt) {
      bf16x8 kf0 = *reinterpret_cast<const bf16x8*>(Kc + (16 * tt + lr) * 128 + 16 * ((lk + 0) ^ (lr & 7)));
      bf16x8 kf1 = *reinterpret_cast<const bf16x8*>(Kc + (16 * tt + lr) * 128 + 16 * ((lk + 4) ^ (lr & 7)));
#pragma unroll
      for (int s = 0; s < 2; ++s) {
        if (!act[s]) continue;
        sacc[s][tt] = __builtin_amdgcn_mfma_f32_16x16x32_bf16(kf0, qf[s][0], sacc[s][tt], 0, 0, 0);
        sacc[s][tt] = __builtin_amdgcn_mfma_f32_16x16x32_bf16(kf1, qf[s][1], sacc[s][tt], 0, 0, 0);
      }
    }

#pragma unroll
    for (int s = 0; s < 2; ++s) {
      if (!act[s]) continue;
      const int qw = qw2[s];
      char* const PsSB = (char*)(Ps[s][w]);
      const int qg = qw + lr;
      float sv[4][4];
      if (kbase + 63 > qw) {
#pragma unroll
        for (int tt = 0; tt < 4; ++tt)
#pragma unroll
          for (int r = 0; r < 4; ++r) {
            const int kg = kbase + 16 * tt + 4 * lk + r;
            sv[tt][r] = (kg > qg) ? -1e30f : sacc[s][tt][r];
          }
      } else {
#pragma unroll
        for (int tt = 0; tt < 4; ++tt)
#pragma unroll
          for (int r = 0; r < 4; ++r) sv[tt][r] = sacc[s][tt][r];
      }
      float tm = sv[0][0];
#pragma unroll
      for (int tt = 0; tt < 4; ++tt)
#pragma unroll
        for (int r = 0; r < 4; ++r) tm = fmaxf(tm, sv[tt][r]);
      tm = fmaxf(tm, __shfl_xor(tm, 16));
      tm = fmaxf(tm, __shfl_xor(tm, 32));
      float mref = mrun[s];
      if (__any(tm > mref + 8.0f)) {            // defer-max
        const float mnew  = fmaxf(mref, tm);
        const float alpha = exp2f(mref - mnew);
#pragma unroll
        for (int r = 0; r < 4; ++r) {
          const float ar = __shfl(alpha, 4 * lk + r);
#pragma unroll
          for (int dn = 0; dn < 4; ++dn) oacc[s][dn][r] *= ar;
        }
        lrun[s] *= alpha;
        mrun[s] = mnew;
        mref = mnew;
      }
      float ts = 0.0f;
      unsigned short pb[4][4];
#pragma unroll
      for (int tt = 0; tt < 4; ++tt)
#pragma unroll
        for (int r = 0; r < 4; ++r) {
          const float p = exp2f(sv[tt][r] - mref);   // bounded by 2^8
          ts += p;
          pb[tt][r] = __builtin_bit_cast(unsigned short, static_cast<__bf16>(p));
        }
      ts += __shfl_xor(ts, 16);
      ts += __shfl_xor(ts, 32);
      lrun[s] += ts;
#pragma unroll
      for (int tt = 0; tt < 4; ++tt) {
        u16x4 pw = {pb[tt][0], pb[tt][1], pb[tt][2], pb[tt][3]};
        *reinterpret_cast<u16x4*>(
            PsSB + lr * 128 + ((32 * tt + 8 * lk) ^ (16 * (lr & 7)))) = pw;
      }
    }

    // order P stores before the TBAA-distinct typed re-reads below
    asm volatile("" ::: "memory");

#pragma unroll
    for (int kk = 0; kk < 2; ++kk) {
      bf16x8 vf[4];
#pragma unroll
      for (int dn = 0; dn < 4; ++dn)
        vf[dn] = *reinterpret_cast<const bf16x8*>(
            Vc + (16 * dn + lr) * 128 + 16 * ((4 * kk + lk) ^ (lr & 7)));
#pragma unroll
      for (int s = 0; s < 2; ++s) {
        if (!act[s]) continue;
        char* const PsSB = (char*)(Ps[s][w]);
        bf16x8 pa = *reinterpret_cast<const bf16x8*>(
            PsSB + lr * 128 + ((64 * kk + 16 * lk) ^ (16 * (lr & 7))));
#pragma unroll
        for (int dn = 0; dn < 4; ++dn)
          oacc[s][dn] = __builtin_amdgcn_mfma_f32_16x16x32_bf16(pa, vf[dn], oacc[s][dn], 0, 0, 0);
      }
    }

    // order PV's P reads before next iteration's P stores (same-wave WAR on Ps)
    asm volatile("" ::: "memory");
  }

#pragma unroll
  for (int s = 0; s < 2; ++s)
#pragma unroll
    for (int r = 0; r < 4; ++r) {
      const float li = 1.0f / __shfl(lrun[s], 4 * lk + r);
      const size_t row = rowB + qw2[s] + 4 * lk + r;
#pragma unroll
      for (int dn = 0; dn < 4; ++dn)
        O[row * DM + hoff + 16 * dn + lr] = f2bf(oacc[s][dn][r] * li);
    }
}

// ---------------- launch ----------------
extern "C" void kernel_launch(void* const* d_in, const int* in_sizes, int n_in,
                              void* d_out, int out_size, void* d_ws, size_t ws_size,
                              hipStream_t stream) {
  const float* x   = (const float*)d_in[0];
  const float* ln1 = (const float*)d_in[1];
  const float* ln2 = (const float*)d_in[2];
  const float* wq  = (const float*)d_in[3];
  const float* wk  = (const float*)d_in[4];
  const float* wv  = (const float*)d_in[5];
  const float* wo  = (const float*)d_in[6];
  const float* w1  = (const float*)d_in[7];
  const float* w2  = (const float*)d_in[8];

  char* ws = (char*)d_ws;
  size_t off = 0;
  auto take = [&](size_t bytes) { void* p = ws + off; off += bytes; return p; };
  unsigned short* wqkb = (unsigned short*)take((size_t)2 * DM * DM * 2);   // 4 MB (Q,K fused)
  unsigned short* wvb  = (unsigned short*)take((size_t)DM * DM * 2);       // 2 MB
  unsigned short* wob  = (unsigned short*)take((size_t)DM * DM * 2);       // 2 MB
  unsigned short* w1b  = (unsigned short*)take((size_t)DFF * DM * 2);      // 8 MB
  unsigned short* w2b  = (unsigned short*)take((size_t)DM * DFF * 2);      // 8 MB
  unsigned short* qk   = (unsigned short*)take((size_t)NROWS * 2 * DM * 2); // 32 MB
  unsigned short* xn   = (unsigned short*)take((size_t)NROWS * DM * 2);    // 16 MB (ln1 out, reused attn-out)
  unsigned short* vtb  = (unsigned short*)take((size_t)DM * NROWS * 2);    // 16 MB V^T [DM][NROWS]
  float*          yb   = (float*)take((size_t)NROWS * DM * 4);             // 32 MB fp32 residual
  unsigned short* hb   = (unsigned short*)take((size_t)NROWS * DFF * 2);   // 64 MB
  unsigned short* yn   = qk;   // ln2 out aliases qk (dead after attn)

  auto cvt = [&](const float* src, unsigned short* dst, size_t n) {
    int n4 = (int)(n / 4);
    k_f2bf<<<dim3((n4 + 255) / 256), dim3(256), 0, stream>>>(src, dst, n4);
  };
  cvt(wq, wqkb, (size_t)DM * DM);
  cvt(wk, wqkb + (size_t)DM * DM, (size_t)DM * DM);
  cvt(wv, wvb, (size_t)DM * DM);
  cvt(wo, wob, (size_t)DM * DM);
  cvt(w1, w1b, (size_t)DFF * DM);
  cvt(w2, w2b, (size_t)DM * DFF);

  k_rmsnorm<<<dim3(NROWS), dim3(256), 0, stream>>>(x, ln1, xn);

  // fused QK projection (EPI3: Q columns pre-scaled), 128x256 tile, BK=32
  k_gemm_nt<3, 256, 32><<<dim3(2 * DM / 256, NROWS / 128), dim3(256), 0, stream>>>(
      xn, wqkb, qk, nullptr, NROWS, 2 * DM, DM);

  // V^T directly: VT[DM][NROWS] = wv @ xn^T (operands swapped), 128x128, BK=64
  k_gemm_nt<0, 128, 64><<<dim3(NROWS / 128, DM / 128), dim3(256), 0, stream>>>(
      wvb, xn, vtb, nullptr, DM, NROWS, DM);

  k_attn<<<dim3(HEADS, 16, BATCH), dim3(256), 0, stream>>>(qk, vtb, xn);

  // WO projection + residual: 128x128, BK=64
  k_gemm_nt<1, 128, 64><<<dim3(DM / 128, NROWS / 128), dim3(256), 0, stream>>>(
      xn, wob, yb, x, NROWS, DM, DM);

  k_rmsnorm<<<dim3(NROWS), dim3(256), 0, stream>>>(yb, ln2, yn);

  // FFN1: 128x256 tile, BK=32 (grid 16x64 = 1024 blocks, 3 blocks/CU)
  k_gemm_nt<2, 256, 32><<<dim3(DFF / 256, NROWS / 128), dim3(256), 0, stream>>>(
      yn, w1b, hb, nullptr, NROWS, DFF, DM);
  // FFN2 + residual -> d_out: 128x128, BK=64 (64 barriers instead of 128)
  k_gemm_nt<1, 128, 64><<<dim3(DM / 128, NROWS / 128), dim3(256), 0, stream>>>(
      hb, w2b, (float*)d_out, yb, NROWS, DM, DFF);
}

// Round 17
// 378.832 us; speedup vs baseline: 1.3981x; 1.0321x over previous
//
#include <hip/hip_runtime.h>

#define DM    1024
#define DFF   4096
#define SEQ   2048
#define BATCH 4
#define NROWS (BATCH * SEQ)   // 8192
#define HEADS 16
#define DKH   64
#define KSTR  (2 * DM)        // fused QK row stride

typedef __attribute__((ext_vector_type(4))) float          f32x4;
typedef __attribute__((ext_vector_type(8))) __bf16         bf16x8;
typedef __attribute__((ext_vector_type(8))) unsigned short u16x8;
typedef __attribute__((ext_vector_type(4))) unsigned short u16x4;

static __device__ __forceinline__ unsigned short f2bf(float f) {
  unsigned u = __builtin_bit_cast(unsigned, f);
  u += 0x7fffu + ((u >> 16) & 1u);   // round-to-nearest-even
  return (unsigned short)(u >> 16);
}

// ---------------- fp32 -> bf16 weight conversion (all 6 tensors, 1 launch) ----------------
struct CvtJobs {
  const float* src[6];
  unsigned short* dst[6];
};
// segment sizes in float4 units: wq,wk,wv,wo = 1M elems each (262144 f4),
// w1,w2 = 4M elems each (1048576 f4). cumulative ends:
__constant__ const unsigned c_cum[6] = {262144u, 524288u, 786432u, 1048576u, 2097152u, 3145728u};

__global__ __launch_bounds__(256) void k_f2bf_all(CvtJobs jobs) {
  unsigned i = blockIdx.x * blockDim.x + threadIdx.x;
  if (i >= 3145728u) return;
  int j = 0;
#pragma unroll
  for (int s = 0; s < 6; ++s) j += (i >= c_cum[s]) ? 1 : 0;
  const unsigned base = (j == 0) ? 0u : c_cum[j - 1];
  const unsigned loc  = i - base;
  float4 v = reinterpret_cast<const float4*>(jobs.src[j])[loc];
  ushort4 o;
  o.x = f2bf(v.x); o.y = f2bf(v.y); o.z = f2bf(v.z); o.w = f2bf(v.w);
  reinterpret_cast<ushort4*>(jobs.dst[j])[loc] = o;
}

// ---------------- RMSNorm: fp32 in -> bf16 out ----------------
__global__ __launch_bounds__(256) void k_rmsnorm(const float* __restrict__ x,
                                                 const float* __restrict__ w,
                                                 unsigned short* __restrict__ out) {
  const int row = blockIdx.x;
  const float4 v = reinterpret_cast<const float4*>(x + (size_t)row * DM)[threadIdx.x];
  float ss = v.x * v.x + v.y * v.y + v.z * v.z + v.w * v.w;
#pragma unroll
  for (int off = 32; off > 0; off >>= 1) ss += __shfl_down(ss, off);
  __shared__ float red[4];
  if ((threadIdx.x & 63) == 0) red[threadIdx.x >> 6] = ss;
  __syncthreads();
  const float tot  = red[0] + red[1] + red[2] + red[3];
  const float rden = rsqrtf(tot * (1.0f / DM) + 1e-5f);
  const float4 wv = reinterpret_cast<const float4*>(w)[threadIdx.x];
  ushort4 o;
  o.x = f2bf(v.x * wv.x * rden);
  o.y = f2bf(v.y * wv.y * rden);
  o.z = f2bf(v.z * wv.z * rden);
  o.w = f2bf(v.w * wv.w * rden);
  reinterpret_cast<ushort4*>(out + (size_t)row * DM)[threadIdx.x] = o;
}

// ---------------- NT GEMM: C(MxN) = A(MxK,bf16) * B(NxK,bf16)^T ----------------
// Round-9-proven structure, templated on tile width TN (128/256) and K-step
// BK (32/64). 128xTN tile, 4 waves (2x2); double-buffered 2-phase K-loop;
// row-major LDS with COALESCED staging + granule XOR.
// r10 lesson: never trade staging coalescing for LDS-conflict-freedom.
// r13: TN=256 (only when grid >= 2 blocks/CU). r16: BK=64 for TN=128
// instances (barrier-stall bound; halves barriers/FLOP; per-kk fragment
// loads keep VGPR under the 2-wave cap -- r14 spill lesson).
// EPI: 0 bf16, 1 fp32+res, 2 gelu, 3 Q-prescale.
template <int EPI, int TN, int BK>
__global__ __launch_bounds__(256, 2) void k_gemm_nt(const unsigned short* __restrict__ A,
                                                    const unsigned short* __restrict__ B,
                                                    void* __restrict__ Cv,
                                                    const float* __restrict__ res,
                                                    int M, int N, int K) {
  constexpr int NW = TN / 128;            // B-tile row multiple
  alignas(16) __shared__ unsigned short As[2][128 * BK];
  alignas(16) __shared__ unsigned short Bs[2][128 * NW * BK];
  const int t  = threadIdx.x;
  const int w  = t >> 6;
  const int l  = t & 63;
  const int wr = w >> 1, wc = w & 1;
  const int lr = l & 15, lk = l >> 4;

  const unsigned bid = blockIdx.y * gridDim.x + blockIdx.x;
  const unsigned cpx = (gridDim.x * gridDim.y) >> 3;
  const unsigned sw  = (bid & 7) * cpx + (bid >> 3);
  const int m0 = (int)(sw / gridDim.x) * 128;
  const int n0 = (int)(sw % gridDim.x) * TN;

  auto stage = [&](int buf, int k0) {
    if constexpr (BK == 32) {
      const int srow = t >> 2;                  // 0..63, 4 lanes per 64B row
      const int sgr  = (t & 3) ^ (srow & 3);    // pre-swizzled source granule
#pragma unroll
      for (int r = 0; r < 2; ++r) {
        const unsigned short* ga = A + (size_t)(m0 + r * 64 + srow) * K + k0 + 8 * sgr;
        __builtin_amdgcn_global_load_lds((__attribute__((address_space(1))) void*)ga,
                                         (__attribute__((address_space(3))) void*)(&As[buf][r * 2048 + w * 512]),
                                         16, 0, 0);
      }
#pragma unroll
      for (int r = 0; r < 2 * NW; ++r) {
        const unsigned short* gb = B + (size_t)(n0 + r * 64 + srow) * K + k0 + 8 * sgr;
        __builtin_amdgcn_global_load_lds((__attribute__((address_space(1))) void*)gb,
                                         (__attribute__((address_space(3))) void*)(&Bs[buf][r * 2048 + w * 512]),
                                         16, 0, 0);
      }
    } else {
      // BK == 64 (TN==128): 128B rows, 8 lanes per row; 4 issues cover 128 rows
      const int srow8 = l >> 3;                 // row within wave's 8-row group
      const int g     = l & 7;
#pragma unroll
      for (int i = 0; i < 4; ++i) {
        const int row = i * 32 + w * 8 + srow8;
        const int sg  = g ^ (row & 7);          // pre-swizzled source granule
        const unsigned short* ga = A + (size_t)(m0 + row) * K + k0 + 8 * sg;
        __builtin_amdgcn_global_load_lds((__attribute__((address_space(1))) void*)ga,
                                         (__attribute__((address_space(3))) void*)(&As[buf][i * 2048 + w * 512]),
                                         16, 0, 0);
        const unsigned short* gb = B + (size_t)(n0 + row) * K + k0 + 8 * sg;
        __builtin_amdgcn_global_load_lds((__attribute__((address_space(1))) void*)gb,
                                         (__attribute__((address_space(3))) void*)(&Bs[buf][i * 2048 + w * 512]),
                                         16, 0, 0);
      }
    }
  };

  f32x4 acc[4][4 * NW] = {};

  stage(0, 0);
  const int nIt = K / BK;
  for (int it = 0; it < nIt; ++it) {
    const int buf = it & 1;
    __syncthreads();                          // drains vmcnt -> buf ready; WAR-safe
    if (it + 1 < nIt) stage(buf ^ 1, (it + 1) * BK);

    if constexpr (BK == 32) {
      bf16x8 af[4], bf[4 * NW];
#pragma unroll
      for (int m = 0; m < 4; ++m)
        af[m] = *reinterpret_cast<const bf16x8*>(
            &As[buf][(wr * 64 + m * 16 + lr) * 32 + 8 * (lk ^ (lr & 3))]);
#pragma unroll
      for (int n = 0; n < 4 * NW; ++n)
        bf[n] = *reinterpret_cast<const bf16x8*>(
            &Bs[buf][(wc * 64 * NW + n * 16 + lr) * 32 + 8 * (lk ^ (lr & 3))]);
#pragma unroll
      for (int m = 0; m < 4; ++m)
#pragma unroll
        for (int n = 0; n < 4 * NW; ++n)
          acc[m][n] = __builtin_amdgcn_mfma_f32_16x16x32_bf16(af[m], bf[n], acc[m][n], 0, 0, 0);
    } else {
      // BK == 64: two K=32 slices; load fragments per-slice to bound VGPR
#pragma unroll
      for (int kk = 0; kk < 2; ++kk) {
        bf16x8 af[4], bf[4];
#pragma unroll
        for (int m = 0; m < 4; ++m)
          af[m] = *reinterpret_cast<const bf16x8*>(
              &As[buf][(wr * 64 + m * 16 + lr) * 64 + 8 * ((4 * kk + lk) ^ (lr & 7))]);
#pragma unroll
        for (int n = 0; n < 4; ++n)
          bf[n] = *reinterpret_cast<const bf16x8*>(
              &Bs[buf][(wc * 64 + n * 16 + lr) * 64 + 8 * ((4 * kk + lk) ^ (lr & 7))]);
#pragma unroll
        for (int m = 0; m < 4; ++m)
#pragma unroll
          for (int n = 0; n < 4; ++n)
            acc[m][n] = __builtin_amdgcn_mfma_f32_16x16x32_bf16(af[m], bf[n], acc[m][n], 0, 0, 0);
      }
    }
  }

#pragma unroll
  for (int m = 0; m < 4; ++m) {
#pragma unroll
    for (int n = 0; n < 4 * NW; ++n) {
#pragma unroll
      for (int r = 0; r < 4; ++r) {
        const size_t row = (size_t)(m0 + wr * 64 + m * 16 + lk * 4 + r);
        const size_t col = (size_t)(n0 + wc * 64 * NW + n * 16 + lr);
        const float a = acc[m][n][r];
        if constexpr (EPI == 0) {
          ((unsigned short*)Cv)[row * N + col] = f2bf(a);
        } else if constexpr (EPI == 1) {
          ((float*)Cv)[row * N + col] = a + res[row * N + col];
        } else if constexpr (EPI == 2) {
          // GELU, tanh/exp2 form: g = h - h/(exp2(h*(a1+b1*h^2))+1)
          const float h2 = a * a;
          const float e  = exp2f(a * (2.30221535f + 0.10295355f * h2));
          const float g  = a - a / (e + 1.0f);
          ((unsigned short*)Cv)[row * N + col] = f2bf(g);
        } else {
          const float sc = (col < DM) ? 0.18033688011f : 1.0f;  // 0.125*log2(e) on Q
          ((unsigned short*)Cv)[row * N + col] = f2bf(a * sc);
        }
      }
    }
  }
}

// ---------------- Flash causal attention (64-row folded q-pairs) ----------------
// r13-proven structure (112us, 68 VGPR, 48KB LDS, 3 blocks/CU).
// grid (HEADS, 16 pairs, BATCH) = 1024 blocks, 4 waves. Pair p handles 64-row
// q-tiles (p, 31-p); blockIdx.x=h keeps all pair-blocks of one (b,h) on one
// XCD. Q pre-scaled by 0.125*log2e. r14 lesson: LDS/occupancy squeezes spill.
// ROUND-17: (a) softmax reductions tree-ified -- fmax tree depth 15->3 (clang
// fuses nested fmaxf triples to v_max3_f32), sum tree depth 16->4; these
// serial chains were the dominant latency (fp max/add not reassociated by
// the compiler). (b) s_setprio(1) around MFMA clusters (T5, attn-positive).
__global__ __launch_bounds__(256, 3) void k_attn(const unsigned short* __restrict__ QK,
                                                 const unsigned short* __restrict__ VT,
                                                 unsigned short* __restrict__ O) {
  const int h   = blockIdx.x;
  const int qtA = blockIdx.y;                 // 0..15
  const int qtB = 31 - qtA;                   // 31..16
  const int b   = blockIdx.z;
  const int t  = threadIdx.x, w = t >> 6, l = t & 63;
  const int lr = l & 15, lk = l >> 4;
  const size_t rowB = (size_t)b * SEQ;
  const int hoff  = h * DKH;
  const int qw2[2] = { qtA * 64 + 16 * w, qtB * 64 + 16 * w };

  alignas(16) __shared__ unsigned short Ks[2][64 * 64];    // 16 KB
  alignas(16) __shared__ unsigned short Vt[2][64 * 64];    // 16 KB
  alignas(16) __shared__ unsigned short Ps[2][4][16 * 64]; // 16 KB

  char* const KsB = (char*)Ks;
  char* const VtB = (char*)Vt;

  auto stage = [&](int buf, int kb2) {
#pragma unroll
    for (int half = 0; half < 2; ++half) {
      const int srow = w * 16 + half * 8 + (l >> 3);
      const int sgr  = (l & 7) ^ (srow & 7);   // pre-swizzled source granule
      const unsigned short* gk = QK + (size_t)(rowB + kb2 + srow) * KSTR + DM + hoff + 8 * sgr;
      __builtin_amdgcn_global_load_lds((__attribute__((address_space(1))) void*)gk,
                                       (__attribute__((address_space(3))) void*)(KsB + buf * 8192 + w * 2048 + half * 1024),
                                       16, 0, 0);
      const unsigned short* gv = VT + (size_t)(hoff + srow) * NROWS + rowB + kb2 + 8 * sgr;
      __builtin_amdgcn_global_load_lds((__attribute__((address_space(1))) void*)gv,
                                       (__attribute__((address_space(3))) void*)(VtB + buf * 8192 + w * 2048 + half * 1024),
                                       16, 0, 0);
    }
  };

  bf16x8 qf[2][2];
#pragma unroll
  for (int s = 0; s < 2; ++s)
#pragma unroll
    for (int kk = 0; kk < 2; ++kk)
      qf[s][kk] = *reinterpret_cast<const bf16x8*>(
          QK + (rowB + qw2[s] + lr) * KSTR + hoff + 32 * kk + 8 * lk);

  f32x4 oacc[2][4] = {};
  float mrun[2] = {-1e30f, -1e30f};
  float lrun[2] = {0.0f, 0.0f};

  const int ktmax = qtB;
  stage(0, 0);
  for (int kt = 0; kt <= ktmax; ++kt) {
    const int kbase = kt * 64;
    const int cur   = kt & 1;
    __syncthreads();
    if (kt < ktmax) stage(cur ^ 1, kbase + 64);
    const char* Kc = KsB + cur * 8192;
    const char* Vc = VtB + cur * 8192;

    const bool act[2] = { kbase <= qw2[0] + 15, kbase <= qw2[1] + 15 };

    f32x4 sacc[2][4] = {};
    __builtin_amdgcn_s_setprio(1);
#pragma unroll
    for (int tt = 0; tt < 4; ++tt) {
      bf16x8 kf0 = *reinterpret_cast<const bf16x8*>(Kc + (16 * tt + lr) * 128 + 16 * ((lk + 0) ^ (lr & 7)));
      bf16x8 kf1 = *reinterpret_cast<const bf16x8*>(Kc + (16 * tt + lr) * 128 + 16 * ((lk + 4) ^ (lr & 7)));
#pragma unroll
      for (int s = 0; s < 2; ++s) {
        if (!act[s]) continue;
        sacc[s][tt] = __builtin_amdgcn_mfma_f32_16x16x32_bf16(kf0, qf[s][0], sacc[s][tt], 0, 0, 0);
        sacc[s][tt] = __builtin_amdgcn_mfma_f32_16x16x32_bf16(kf1, qf[s][1], sacc[s][tt], 0, 0, 0);
      }
    }
    __builtin_amdgcn_s_setprio(0);

#pragma unroll
    for (int s = 0; s < 2; ++s) {
      if (!act[s]) continue;
      const int qw = qw2[s];
      char* const PsSB = (char*)(Ps[s][w]);
      const int qg = qw + lr;
      float sv[4][4];
      if (kbase + 63 > qw) {
#pragma unroll
        for (int tt = 0; tt < 4; ++tt)
#pragma unroll
          for (int r = 0; r < 4; ++r) {
            const int kg = kbase + 16 * tt + 4 * lk + r;
            sv[tt][r] = (kg > qg) ? -1e30f : sacc[s][tt][r];
          }
      } else {
#pragma unroll
        for (int tt = 0; tt < 4; ++tt)
#pragma unroll
          for (int r = 0; r < 4; ++r) sv[tt][r] = sacc[s][tt][r];
      }
      // fmax tree (depth 3; nested triples fuse to v_max3_f32)
      const float a0 = fmaxf(fmaxf(sv[0][0], sv[0][1]), sv[0][2]);
      const float a1 = fmaxf(fmaxf(sv[0][3], sv[1][0]), sv[1][1]);
      const float a2 = fmaxf(fmaxf(sv[1][2], sv[1][3]), sv[2][0]);
      const float a3 = fmaxf(fmaxf(sv[2][1], sv[2][2]), sv[2][3]);
      const float a4 = fmaxf(fmaxf(sv[3][0], sv[3][1]), sv[3][2]);
      float tm = fmaxf(fmaxf(fmaxf(a0, a1), a2), fmaxf(fmaxf(a3, a4), sv[3][3]));
      tm = fmaxf(tm, __shfl_xor(tm, 16));
      tm = fmaxf(tm, __shfl_xor(tm, 32));
      float mref = mrun[s];
      if (__any(tm > mref + 8.0f)) {            // defer-max
        const float mnew  = fmaxf(mref, tm);
        const float alpha = exp2f(mref - mnew);
#pragma unroll
        for (int r = 0; r < 4; ++r) {
          const float ar = __shfl(alpha, 4 * lk + r);
#pragma unroll
          for (int dn = 0; dn < 4; ++dn) oacc[s][dn][r] *= ar;
        }
        lrun[s] *= alpha;
        mrun[s] = mnew;
        mref = mnew;
      }
      float p[4][4];
      unsigned short pb[4][4];
#pragma unroll
      for (int tt = 0; tt < 4; ++tt)
#pragma unroll
        for (int r = 0; r < 4; ++r) {
          p[tt][r] = exp2f(sv[tt][r] - mref);   // bounded by 2^8
          pb[tt][r] = __builtin_bit_cast(unsigned short, static_cast<__bf16>(p[tt][r]));
        }
      // pairwise sum tree (depth 4)
      float t0 = (p[0][0] + p[0][1]) + (p[0][2] + p[0][3]);
      float t1 = (p[1][0] + p[1][1]) + (p[1][2] + p[1][3]);
      float t2 = (p[2][0] + p[2][1]) + (p[2][2] + p[2][3]);
      float t3 = (p[3][0] + p[3][1]) + (p[3][2] + p[3][3]);
      float ts = (t0 + t1) + (t2 + t3);
      ts += __shfl_xor(ts, 16);
      ts += __shfl_xor(ts, 32);
      lrun[s] += ts;
#pragma unroll
      for (int tt = 0; tt < 4; ++tt) {
        u16x4 pw = {pb[tt][0], pb[tt][1], pb[tt][2], pb[tt][3]};
        *reinterpret_cast<u16x4*>(
            PsSB + lr * 128 + ((32 * tt + 8 * lk) ^ (16 * (lr & 7)))) = pw;
      }
    }

    // order P stores before the TBAA-distinct typed re-reads below
    asm volatile("" ::: "memory");

#pragma unroll
    for (int kk = 0; kk < 2; ++kk) {
      bf16x8 vf[4];
#pragma unroll
      for (int dn = 0; dn < 4; ++dn)
        vf[dn] = *reinterpret_cast<const bf16x8*>(
            Vc + (16 * dn + lr) * 128 + 16 * ((4 * kk + lk) ^ (lr & 7)));
      __builtin_amdgcn_s_setprio(1);
#pragma unroll
      for (int s = 0; s < 2; ++s) {
        if (!act[s]) continue;
        char* const PsSB = (char*)(Ps[s][w]);
        bf16x8 pa = *reinterpret_cast<const bf16x8*>(
            PsSB + lr * 128 + ((64 * kk + 16 * lk) ^ (16 * (lr & 7))));
#pragma unroll
        for (int dn = 0; dn < 4; ++dn)
          oacc[s][dn] = __builtin_amdgcn_mfma_f32_16x16x32_bf16(pa, vf[dn], oacc[s][dn], 0, 0, 0);
      }
      __builtin_amdgcn_s_setprio(0);
    }

    // order PV's P reads before next iteration's P stores (same-wave WAR on Ps)
    asm volatile("" ::: "memory");
  }

#pragma unroll
  for (int s = 0; s < 2; ++s)
#pragma unroll
    for (int r = 0; r < 4; ++r) {
      const float li = 1.0f / __shfl(lrun[s], 4 * lk + r);
      const size_t row = rowB + qw2[s] + 4 * lk + r;
#pragma unroll
      for (int dn = 0; dn < 4; ++dn)
        O[row * DM + hoff + 16 * dn + lr] = f2bf(oacc[s][dn][r] * li);
    }
}

// ---------------- launch ----------------
extern "C" void kernel_launch(void* const* d_in, const int* in_sizes, int n_in,
                              void* d_out, int out_size, void* d_ws, size_t ws_size,
                              hipStream_t stream) {
  const float* x   = (const float*)d_in[0];
  const float* ln1 = (const float*)d_in[1];
  const float* ln2 = (const float*)d_in[2];
  const float* wq  = (const float*)d_in[3];
  const float* wk  = (const float*)d_in[4];
  const float* wv  = (const float*)d_in[5];
  const float* wo  = (const float*)d_in[6];
  const float* w1  = (const float*)d_in[7];
  const float* w2  = (const float*)d_in[8];

  char* ws = (char*)d_ws;
  size_t off = 0;
  auto take = [&](size_t bytes) { void* p = ws + off; off += bytes; return p; };
  unsigned short* wqkb = (unsigned short*)take((size_t)2 * DM * DM * 2);   // 4 MB (Q,K fused)
  unsigned short* wvb  = (unsigned short*)take((size_t)DM * DM * 2);       // 2 MB
  unsigned short* wob  = (unsigned short*)take((size_t)DM * DM * 2);       // 2 MB
  unsigned short* w1b  = (unsigned short*)take((size_t)DFF * DM * 2);      // 8 MB
  unsigned short* w2b  = (unsigned short*)take((size_t)DM * DFF * 2);      // 8 MB
  unsigned short* qk   = (unsigned short*)take((size_t)NROWS * 2 * DM * 2); // 32 MB
  unsigned short* xn   = (unsigned short*)take((size_t)NROWS * DM * 2);    // 16 MB (ln1 out, reused attn-out)
  unsigned short* vtb  = (unsigned short*)take((size_t)DM * NROWS * 2);    // 16 MB V^T [DM][NROWS]
  float*          yb   = (float*)take((size_t)NROWS * DM * 4);             // 32 MB fp32 residual
  unsigned short* hb   = (unsigned short*)take((size_t)NROWS * DFF * 2);   // 64 MB
  unsigned short* yn   = qk;   // ln2 out aliases qk (dead after attn)

  // one fused weight-conversion dispatch (segment order matches c_cum)
  CvtJobs jobs;
  jobs.src[0] = wq;  jobs.dst[0] = wqkb;
  jobs.src[1] = wk;  jobs.dst[1] = wqkb + (size_t)DM * DM;
  jobs.src[2] = wv;  jobs.dst[2] = wvb;
  jobs.src[3] = wo;  jobs.dst[3] = wob;
  jobs.src[4] = w1;  jobs.dst[4] = w1b;
  jobs.src[5] = w2;  jobs.dst[5] = w2b;
  k_f2bf_all<<<dim3(3145728u / 256u), dim3(256), 0, stream>>>(jobs);

  k_rmsnorm<<<dim3(NROWS), dim3(256), 0, stream>>>(x, ln1, xn);

  // fused QK projection (EPI3: Q columns pre-scaled), 128x256 tile, BK=32
  k_gemm_nt<3, 256, 32><<<dim3(2 * DM / 256, NROWS / 128), dim3(256), 0, stream>>>(
      xn, wqkb, qk, nullptr, NROWS, 2 * DM, DM);

  // V^T directly: VT[DM][NROWS] = wv @ xn^T (operands swapped), 128x128, BK=64
  k_gemm_nt<0, 128, 64><<<dim3(NROWS / 128, DM / 128), dim3(256), 0, stream>>>(
      wvb, xn, vtb, nullptr, DM, NROWS, DM);

  k_attn<<<dim3(HEADS, 16, BATCH), dim3(256), 0, stream>>>(qk, vtb, xn);

  // WO projection + residual: 128x128, BK=64
  k_gemm_nt<1, 128, 64><<<dim3(DM / 128, NROWS / 128), dim3(256), 0, stream>>>(
      xn, wob, yb, x, NROWS, DM, DM);

  k_rmsnorm<<<dim3(NROWS), dim3(256), 0, stream>>>(yb, ln2, yn);

  // FFN1: 128x256 tile, BK=32 (grid 16x64 = 1024 blocks)
  k_gemm_nt<2, 256, 32><<<dim3(DFF / 256, NROWS / 128), dim3(256), 0, stream>>>(
      yn, w1b, hb, nullptr, NROWS, DFF, DM);
  // FFN2 + residual -> d_out: 128x128, BK=64
  k_gemm_nt<1, 128, 64><<<dim3(DM / 128, NROWS / 128), dim3(256), 0, stream>>>(
      hb, w2b, (float*)d_out, yb, NROWS, DM, DFF);
}